// Round 10
// baseline (208.910 us; speedup 1.0000x reference)
//
#include <hip/hip_runtime.h>
#include <hip/hip_fp16.h>

#define Bsz 1024
#define Mm  2048
#define Rr  8192
#define EMAX 32   // ushort slots per E column (col nnz mean ~4.1)
#define SMAX 64   // ushort slots per S row    (row nnz mean ~16.4)

typedef unsigned short ushort_t;

// ---- pass 1: logcTh[s][m][64] (fp16, b-slice-major); zero ecnt + ALL of elist ----
// grid MUST be 512 x 256 = 131072 threads == Rr*EMAX ushorts / 2 (uint32 zeroing)
__global__ __launch_bounds__(256) void transpose_log(
    const float* __restrict__ conc, __half2* __restrict__ logcTh2,
    int* __restrict__ ecnt, unsigned int* __restrict__ elist32)
{
    const int g = blockIdx.x * 256 + threadIdx.x;
    if (g < Rr) ecnt[g] = 0;
    elist32[g] = 0;                        // e=0, m=0 -> harmless pad entries

    __shared__ float tile[64][65];         // [m-off][b-off]
    const int mt = (blockIdx.x % (Mm / 64)) * 64;
    const int bt = (blockIdx.x / (Mm / 64)) * 64;
    const int lm = threadIdx.x & 63;
    const int w  = threadIdx.x >> 6;
    for (int i = w; i < 64; i += 4)
        tile[lm][i] = __logf(conc[(size_t)(bt + i) * Mm + mt + lm]);
    __syncthreads();
    const int s       = bt >> 7;           // b-slice (128 b each)
    const int colbase = (bt & 127) >> 1;   // 0 or 32 (half2 cols within slice)
    __half2* dst = logcTh2 + (size_t)s * (Mm * 64);
    for (int idx = threadIdx.x; idx < 64 * 32; idx += 256) {
        const int j  = idx >> 5;           // m offset
        const int bp = idx & 31;           // half2 col within this 64-b tile
        dst[(mt + j) * 64 + colbase + bp] =
            __floats2half2_rn(tile[j][2 * bp], tile[j][2 * bp + 1]);
    }
}

// ---- pass 2: grid 4096. Blocks 0..2047 scan E row m; 2048..4095 scan S row m. ----
// At structural ingest ceiling (~49 us for 128 MB dense scan) — do not touch.
__global__ __launch_bounds__(256) void build_lists(
    const int* __restrict__ E, const int* __restrict__ S,
    int* __restrict__ ecnt, ushort_t* __restrict__ elist,
    int* __restrict__ scnt, ushort_t* __restrict__ slist)
{
    __shared__ int n_hits;
    __shared__ int buf[256];
    const int t = threadIdx.x;
    if (t == 0) n_hits = 0;
    __syncthreads();

    if (blockIdx.x < 2048) {               // ---- E scanner ----
        const int m = blockIdx.x;
        const int4* E4 = (const int4*)E + (size_t)m * 2048;
        int4 e[8];
        #pragma unroll
        for (int u = 0; u < 8; ++u) e[u] = E4[t + 256 * u];
        #pragma unroll
        for (int u = 0; u < 8; ++u) {
            const int r0 = (t + 256 * u) << 2;
            int ev[4] = {e[u].x, e[u].y, e[u].z, e[u].w};
            #pragma unroll
            for (int q = 0; q < 4; ++q)
                if (ev[q]) {
                    int i = atomicAdd(&n_hits, 1);        // LDS atomic
                    if (i < 256) buf[i] = (ev[q] << 13) | (r0 + q);
                }
        }
        __syncthreads();
        const int en = min(n_hits, 256);
        if (t < en) {
            int wv = buf[t];
            int r  = wv & 0x1FFF;
            int ev = wv >> 13;
            int slot = atomicAdd(&ecnt[r], 1);            // ~16 atomics/block
            if (slot < EMAX) elist[r * EMAX + slot] = (ushort_t)((ev << 11) | m);
        }
    } else {                               // ---- S scanner (owns row m) ----
        const int m = blockIdx.x - 2048;
        const int4* S4 = (const int4*)S + (size_t)m * 2048;
        int4 s[8];
        #pragma unroll
        for (int u = 0; u < 8; ++u) s[u] = S4[t + 256 * u];
        #pragma unroll
        for (int u = 0; u < 8; ++u) {
            const int r0 = (t + 256 * u) << 2;
            int sv[4] = {s[u].x, s[u].y, s[u].z, s[u].w};
            #pragma unroll
            for (int q = 0; q < 4; ++q)
                if (sv[q]) {
                    int i = atomicAdd(&n_hits, 1);        // LDS atomic
                    if (i < 256) buf[i] = ((sv[q] + 2) << 13) | (r0 + q);
                }
        }
        __syncthreads();
        const int sn = min(n_hits, SMAX);
        if (t == 0) scnt[m] = sn;
        if (t < SMAX)                                     // fill ALL slots: pads safe
            slist[m * SMAX + t] = (t < sn) ? (ushort_t)buf[t]
                                           : (ushort_t)0x4000;   // enc 2 -> s=0
    }
}

// ---- pass 3 (fused): out[b][m] = sum_j s_j * k_{r_j} * exp(sum_i e_i*logc[m_i][b])
// No VT materialization. slice s = blockIdx&7 (XCD pin: logc slice 512KB L2-hot).
// S-entries processed in pairs: 2 independent E-row pipelines, >=8 gathers in flight.
__global__ __launch_bounds__(256) void fused_out(
    const __half2* __restrict__ logcTh2, const float* __restrict__ kvec,
    const int* __restrict__ ecnt, const ushort_t* __restrict__ elist,
    const int* __restrict__ scnt, const ushort_t* __restrict__ slist,
    float* __restrict__ out)
{
    __shared__ float tile[8][130];               // [m-local][b-local], pad vs conflicts
    const int s   = blockIdx.x & 7;
    const int mch = blockIdx.x >> 3;             // 0..255, 8 m each
    const int col = threadIdx.x & 63;            // half2 col within slice
    const int wm  = threadIdx.x >> 6;
    const __half2* lc = logcTh2 + (size_t)s * (Mm * 64);
    const int m0 = mch * 8;

    unsigned w; float2 g;
    #define EG(word, acc)                                                  \
        w = (unsigned)(word);                                              \
        g = __half22float2(lc[(w & 0x7FF) * 64 + col]);                    \
        acc.x += (float)((w & 0xFFFF) >> 11) * g.x;                        \
        acc.y += (float)((w & 0xFFFF) >> 11) * g.y;                        \
        g = __half22float2(lc[((w >> 16) & 0x7FF) * 64 + col]);            \
        acc.x += (float)(w >> 27) * g.x;                                   \
        acc.y += (float)(w >> 27) * g.y;

    for (int i = 0; i < 2; ++i) {
        const int ml = i * 4 + wm;
        const int m  = m0 + ml;
        const ushort_t* srow = slist + (m << 6);
        const int cnt = scnt[m];                 // wave-uniform exact count
        float2 a = make_float2(0.f, 0.f);
        unsigned pr = *(const unsigned*)(srow);  // prefetched pair
        for (int j = 0; j < cnt; j += 2) {
            const unsigned cur = pr;
            if (j + 2 < cnt) pr = *(const unsigned*)(srow + j + 2);
            const unsigned eA = cur & 0xFFFFu, eB = cur >> 16;   // pad 0x4000 -> s=0
            const int   rA  = eA & 0x1FFF,  rB  = eB & 0x1FFF;
            const float swA = (float)((int)(eA >> 13) - 2);
            const float swB = (float)((int)(eB >> 13) - 2);
            const ushort_t* erA = elist + (rA << 5);
            const ushort_t* erB = elist + (rB << 5);
            const int ceA = ecnt[rA], ceB = ecnt[rB];
            const float kA = kvec[rA], kB = kvec[rB];
            int2 GA = *(const int2*)erA;         // 4 E-entries each (zero-padded)
            int2 GB = *(const int2*)erB;
            float2 lgA = make_float2(0.f, 0.f), lgB = make_float2(0.f, 0.f);
            EG(GA.x, lgA) EG(GA.y, lgA)
            EG(GB.x, lgB) EG(GB.y, lgB)
            for (int tt = 4; tt < ceA; tt += 4) {   // wave-uniform tails (~39%)
                int2 T = *(const int2*)(erA + tt);
                EG(T.x, lgA) EG(T.y, lgA)
            }
            for (int tt = 4; tt < ceB; tt += 4) {
                int2 T = *(const int2*)(erB + tt);
                EG(T.x, lgB) EG(T.y, lgB)
            }
            a.x += swA * kA * __expf(lgA.x) + swB * kB * __expf(lgB.x);
            a.y += swA * kA * __expf(lgA.y) + swB * kB * __expf(lgB.y);
        }
        tile[ml][2 * col]     = a.x;             // 2 lanes/bank -> free
        tile[ml][2 * col + 1] = a.y;
    }
    #undef EG
    __syncthreads();
    // store 128 b x 8 m: thread -> (b-local, 4-float group); full 64B lines per wave
    const int bl = threadIdx.x >> 1;
    const int fl = (threadIdx.x & 1) * 4;
    float4 vv = make_float4(tile[fl + 0][bl], tile[fl + 1][bl],
                            tile[fl + 2][bl], tile[fl + 3][bl]);
    *(float4*)(out + (size_t)(s * 128 + bl) * Mm + m0 + fl) = vv;
}

extern "C" void kernel_launch(void* const* d_in, const int* in_sizes, int n_in,
                              void* d_out, int out_size, void* d_ws, size_t ws_size,
                              hipStream_t stream) {
    const float* conc = (const float*)d_in[0];
    const int*   E    = (const int*)d_in[1];
    const int*   S    = (const int*)d_in[2];
    const float* kvec = (const float*)d_in[3];
    float* out = (float*)d_out;

    // ws: logcTh fp16 (4 MB) | ecnt | scnt | elist u16 | slist u16   (~5.3 MB)
    __half2* logcTh2 = (__half2*)d_ws;
    int*    ecnt     = (int*)((char*)d_ws + (size_t)Mm * Bsz * sizeof(__half));
    int*    scnt     = ecnt + Rr;
    ushort_t* elist  = (ushort_t*)(scnt + Mm);
    ushort_t* slist  = elist + Rr * EMAX;
    const size_t need = (size_t)Mm * Bsz * sizeof(__half)
                      + (size_t)(Rr + Mm) * sizeof(int)
                      + (size_t)(Rr * EMAX + Mm * SMAX) * sizeof(ushort_t);
    if (ws_size < need) return;

    transpose_log<<<512, 256, 0, stream>>>(conc, logcTh2, ecnt, (unsigned int*)elist);
    build_lists<<<4096, 256, 0, stream>>>(E, S, ecnt, elist, scnt, slist);
    fused_out<<<2048, 256, 0, stream>>>(logcTh2, kvec, ecnt, elist, scnt, slist, out);
}

// Round 11
// 182.280 us; speedup vs baseline: 1.1461x; 1.1461x over previous
//
#include <hip/hip_runtime.h>
#include <hip/hip_fp16.h>

#define Bsz 1024
#define Mm  2048
#define Rr  8192
#define EMAX 32   // ushort slots per E column (col nnz mean ~4.1)
#define SMAX 64   // ushort slots per S row    (row nnz mean ~16.4)

typedef unsigned short ushort_t;

// ---- pass 0: zero ecnt only (32 KB). elist pads handled by weight-masking. ----
__global__ __launch_bounds__(256) void zero_ecnt(int* __restrict__ p) {
    p[blockIdx.x * 256 + threadIdx.x] = 0;       // grid 32 -> 8192
}

// ---- pass 1 (merged): blocks 0..511 transpose+log; 512..2559 S-scan; 2560..4607 E-scan.
// Transpose hides under the scan's miss-latency wall (all roles independent).
__global__ __launch_bounds__(256) void prep_kernel(
    const float* __restrict__ conc, const int* __restrict__ E, const int* __restrict__ S,
    __half2* __restrict__ logcTh2, int* __restrict__ ecnt, ushort_t* __restrict__ elist,
    int* __restrict__ scnt, ushort_t* __restrict__ slist)
{
    __shared__ float tile[64][65];               // transpose role (16.6 KB)
    __shared__ int n_hits;                       // scan roles
    __shared__ int buf[256];
    const int bid = blockIdx.x;
    const int t   = threadIdx.x;

    if (bid < 512) {                             // ---- transpose + log -> fp16 ----
        const int mt = (bid & 31) * 64;          // Mm/64 = 32
        const int bt = (bid >> 5) * 64;
        const int lm = t & 63;
        const int w  = t >> 6;
        for (int i = w; i < 64; i += 4)
            tile[lm][i] = __logf(conc[(size_t)(bt + i) * Mm + mt + lm]);
        __syncthreads();
        const int s       = bt >> 7;             // b-slice (128 b)
        const int colbase = (bt & 127) >> 1;
        __half2* dst = logcTh2 + (size_t)s * (Mm * 64);
        for (int idx = t; idx < 64 * 32; idx += 256) {
            const int j = idx >> 5, bp = idx & 31;
            dst[(mt + j) * 64 + colbase + bp] =
                __floats2half2_rn(tile[j][2 * bp], tile[j][2 * bp + 1]);
        }
    } else if (bid < 2560) {                     // ---- S-scan: owns row m ----
        const int m = bid - 512;
        if (t == 0) n_hits = 0;
        __syncthreads();
        const int4* S4 = (const int4*)S + (size_t)m * 2048;
        int4 sv[8];
        #pragma unroll
        for (int u = 0; u < 8; ++u) sv[u] = S4[t + 256 * u];
        #pragma unroll
        for (int u = 0; u < 8; ++u) {
            const int r0 = (t + 256 * u) << 2;
            int v[4] = {sv[u].x, sv[u].y, sv[u].z, sv[u].w};
            #pragma unroll
            for (int q = 0; q < 4; ++q)
                if (v[q]) {
                    int i = atomicAdd(&n_hits, 1);          // LDS atomic
                    if (i < 256) buf[i] = ((v[q] + 2) << 13) | (r0 + q);
                }
        }
        __syncthreads();
        const int sn = min(n_hits, SMAX);
        if (t == 0) scnt[m] = sn;
        if (t < SMAX)                            // write ALL slots: pads are safe
            slist[m * SMAX + t] = (t < sn) ? (ushort_t)buf[t]
                                           : (ushort_t)0x4000;   // enc 2 -> s=0
    } else {                                     // ---- E-scan: owns row m ----
        const int m = bid - 2560;
        if (t == 0) n_hits = 0;
        __syncthreads();
        const int4* E4 = (const int4*)E + (size_t)m * 2048;
        int4 ev[8];
        #pragma unroll
        for (int u = 0; u < 8; ++u) ev[u] = E4[t + 256 * u];
        #pragma unroll
        for (int u = 0; u < 8; ++u) {
            const int r0 = (t + 256 * u) << 2;
            int v[4] = {ev[u].x, ev[u].y, ev[u].z, ev[u].w};
            #pragma unroll
            for (int q = 0; q < 4; ++q)
                if (v[q]) {
                    int i = atomicAdd(&n_hits, 1);          // LDS atomic
                    if (i < 256) buf[i] = (v[q] << 13) | (r0 + q);
                }
        }
        __syncthreads();
        const int en = min(n_hits, 256);
        if (t < en) {
            int wv = buf[t];
            int r  = wv & 0x1FFF;
            int e  = wv >> 13;
            int slot = atomicAdd(&ecnt[r], 1);              // ~16 atomics/block
            if (slot < EMAX) elist[r * EMAX + slot] = (ushort_t)((e << 11) | m);
        }
    }
}

// ---- pass 2: VTh[s][r][64] = k[r]*exp(sum e*logcTh[s][m][64]) ----
// Batched: all 8 rows' scalar loads first (one latency hop), then 32+ gathers.
// Pad entries are garbage (elist not zeroed) -> weights validity-masked; addr &0x7FF in-bounds.
__global__ __launch_bounds__(256) void rates_kernel(
    const __half2* __restrict__ logcTh2, const float* __restrict__ kvec,
    const int* __restrict__ ecnt, const ushort_t* __restrict__ elist,
    __half2* __restrict__ VTh)
{
    const int s   = blockIdx.x & 7;              // XCD pin: logc slice 512 KB L2-hot
    const int rch = blockIdx.x >> 3;             // 0..255, 32 r each
    const int col = threadIdx.x & 63;
    const int wr  = __builtin_amdgcn_readfirstlane(threadIdx.x >> 6);
    const __half2* lc = logcTh2 + (size_t)s * (Mm * 64);
    __half2* vt = VTh + (size_t)s * (Rr * 64);
    const int rb = rch * 32 + wr * 8;

    int  cnt[8]; int2 L0[8]; float kk[8];        // batch phase: independent s_loads
    #pragma unroll
    for (int i = 0; i < 8; ++i) {
        const int r = rb + i;
        cnt[i] = ecnt[r];
        L0[i]  = *(const int2*)(elist + (r << 5));
        kk[i]  = kvec[r];
    }
    float2 acc[8];
    unsigned w; float2 g; float v0, v1;
    #define EG2(word, c0, c1, A)                                               \
        w = (unsigned)(word);                                                  \
        v0 = (c0) ? (float)((w & 0xFFFF) >> 11) : 0.f;                         \
        v1 = (c1) ? (float)(w >> 27) : 0.f;                                    \
        g = __half22float2(lc[(w & 0x7FF) * 64 + col]);                        \
        A.x += v0 * g.x;  A.y += v0 * g.y;                                     \
        g = __half22float2(lc[((w >> 16) & 0x7FF) * 64 + col]);                \
        A.x += v1 * g.x;  A.y += v1 * g.y;
    #pragma unroll
    for (int i = 0; i < 8; ++i) {                // 32 gathers, one dependency level
        acc[i] = make_float2(0.f, 0.f);
        EG2(L0[i].x, cnt[i] > 0, cnt[i] > 1, acc[i])
        EG2(L0[i].y, cnt[i] > 2, cnt[i] > 3, acc[i])
    }
    #pragma unroll
    for (int i = 0; i < 8; ++i) {                // rare wave-uniform tails
        for (int j = 4; j < cnt[i]; j += 4) {
            int2 T = *(const int2*)(elist + ((rb + i) << 5) + j);
            EG2(T.x, j + 0 < cnt[i], j + 1 < cnt[i], acc[i])
            EG2(T.y, j + 2 < cnt[i], j + 3 < cnt[i], acc[i])
        }
    }
    #undef EG2
    #pragma unroll
    for (int i = 0; i < 8; ++i)
        vt[(rb + i) * 64 + col] =
            __floats2half2_rn(kk[i] * __expf(acc[i].x), kk[i] * __expf(acc[i].y));
}

// ---- pass 3: out[b][m] = sum s*VTh[s][r][64]; batched lists; LDS transpose stores ----
__global__ __launch_bounds__(256) void assemble_kernel(
    const __half2* __restrict__ VTh, const int* __restrict__ scnt,
    const ushort_t* __restrict__ slist, float* __restrict__ out)
{
    __shared__ float tile[128][17];              // [b-local][m-local] 8.5 KB
    const int s   = blockIdx.x & 7;              // same XCD pin as rates
    const int mch = blockIdx.x >> 3;             // 0..127, 16 m each
    const int col = threadIdx.x & 63;
    const int wm  = __builtin_amdgcn_readfirstlane(threadIdx.x >> 6);
    const __half2* vt = VTh + (size_t)s * (Rr * 64);
    const int m0 = mch * 16;

    int scn[4]; int4 W0[4], W1[4];               // batch phase: independent s_loads
    #pragma unroll
    for (int i = 0; i < 4; ++i) {
        const int m = m0 + i * 4 + wm;
        scn[i] = scnt[m];
        W0[i]  = *(const int4*)(slist + (m << 6));
        W1[i]  = *(const int4*)(slist + (m << 6) + 8);
    }
    unsigned w; float2 v; float sw;
    #define SG(word, A)                                                        \
        w = (unsigned)(word);                                                  \
        v = __half22float2(vt[(w & 0x1FFF) * 64 + col]);                       \
        sw = (float)((int)((w & 0xFFFF) >> 13) - 2);                           \
        A.x += sw * v.x;  A.y += sw * v.y;                                     \
        v = __half22float2(vt[((w >> 16) & 0x1FFF) * 64 + col]);               \
        sw = (float)((int)(w >> 29) - 2);                                      \
        A.x += sw * v.x;  A.y += sw * v.y;
    #pragma unroll
    for (int i = 0; i < 4; ++i) {
        const int ml = i * 4 + wm;
        float2 a = make_float2(0.f, 0.f);
        SG(W0[i].x, a) SG(W0[i].y, a) SG(W0[i].z, a) SG(W0[i].w, a)
        SG(W1[i].x, a) SG(W1[i].y, a) SG(W1[i].z, a) SG(W1[i].w, a)
        for (int j = 16; j < scn[i]; j += 8) {   // pads materialized -> safe groups
            int4 T = *(const int4*)(slist + ((m0 + ml) << 6) + j);
            SG(T.x, a) SG(T.y, a) SG(T.z, a) SG(T.w, a)
        }
        tile[2 * col][ml]     = a.x;
        tile[2 * col + 1][ml] = a.y;
    }
    #undef SG
    __syncthreads();
    #pragma unroll
    for (int pass = 0; pass < 2; ++pass) {
        const int bl = (threadIdx.x >> 2) + pass * 64;
        const int fl = threadIdx.x & 3;
        float4 vv = *(const float4*)&tile[bl][fl * 4];
        *(float4*)(out + (size_t)(s * 128 + bl) * Mm + m0 + fl * 4) = vv;
    }
}

extern "C" void kernel_launch(void* const* d_in, const int* in_sizes, int n_in,
                              void* d_out, int out_size, void* d_ws, size_t ws_size,
                              hipStream_t stream) {
    const float* conc = (const float*)d_in[0];
    const int*   E    = (const int*)d_in[1];
    const int*   S    = (const int*)d_in[2];
    const float* kvec = (const float*)d_in[3];
    float* out = (float*)d_out;

    // ws: VTh fp16 (16 MB) | logcTh fp16 (4 MB) | ecnt | scnt | elist u16 | slist u16
    __half2* VTh     = (__half2*)d_ws;
    __half2* logcTh2 = (__half2*)((char*)d_ws + (size_t)Rr * Bsz * sizeof(__half));
    int*    ecnt     = (int*)((char*)logcTh2 + (size_t)Mm * Bsz * sizeof(__half));
    int*    scnt     = ecnt + Rr;
    ushort_t* elist  = (ushort_t*)(scnt + Mm);
    ushort_t* slist  = elist + Rr * EMAX;
    const size_t need = (size_t)Rr * Bsz * sizeof(__half)
                      + (size_t)Mm * Bsz * sizeof(__half)
                      + (size_t)(Rr + Mm) * sizeof(int)
                      + (size_t)(Rr * EMAX + Mm * SMAX) * sizeof(ushort_t);
    if (ws_size < need) return;

    zero_ecnt<<<32, 256, 0, stream>>>(ecnt);
    prep_kernel<<<4608, 256, 0, stream>>>(conc, E, S, logcTh2, ecnt, elist, scnt, slist);
    rates_kernel<<<2048, 256, 0, stream>>>(logcTh2, kvec, ecnt, elist, VTh);
    assemble_kernel<<<1024, 256, 0, stream>>>(VTh, scnt, slist, out);
}